// Round 11
// baseline (295.517 us; speedup 1.0000x reference)
//
#include <hip/hip_runtime.h>
#include <hip/hip_fp16.h>

#define GG 256   // NUM_GRAPHS
#define ZZDIM 32 // Z
#define KK 64    // K
#define EMBD 10  // EMB
#define BPG 4                // scatter blocks per graph
#define SGRID (GG * BPG)     // 1024 scatter blocks
#define SLOTS 64             // slots per 512-thr scatter block (8 lanes each)
#define SPG (BPG * SLOTS)    // 256 slots per graph
#define MAXN 4096            // LDS node-slice capacity (graphs avg ~390 nodes)
#define CAP 16384            // per-graph record segment capacity (avg fill 6250, 24+ sigma)

// Record: rec[i] = (w, bits(colLocal<<17 | row)); row < 2^17 (n=100000), colLocal < 2^15.
// hs is fp16: one 64 B line per node row — each edge gather touches exactly one line.

// ---------------- kernels ----------------

// node ranges per graph (binary search on sorted batch); init cursors + arrival counters
__global__ void lb_kernel(const int* __restrict__ batch, int* __restrict__ lb,
                          int* __restrict__ gcur, int* __restrict__ pcnt, int n) {
    int g = threadIdx.x;  // 256 threads
    int lo = 0, hi = n;
    while (lo < hi) {
        int mid = (lo + hi) >> 1;
        if (batch[mid] < g) lo = mid + 1; else hi = mid;
    }
    lb[g] = lo;
    if (g == 0) lb[GG] = n;
    gcur[g] = g * CAP;
    pcnt[g] = 0;
}

// single-pass counting-bucket, 2048 edges/block, int4/float4 edge reads.
__global__ void __launch_bounds__(512) bucket_kernel(
    const int* __restrict__ row, const int* __restrict__ col, const float* __restrict__ w,
    const int* __restrict__ batch, const int* __restrict__ lb,
    int* __restrict__ gcur, float2* __restrict__ rec, int e) {
    __shared__ int lcnt[GG], lres[GG], loff[GG], lbs[GG];
    if (threadIdx.x < GG) { lcnt[threadIdx.x] = 0; loff[threadIdx.x] = 0; lbs[threadIdx.x] = lb[threadIdx.x]; }
    __syncthreads();
    const long i0 = (long)blockIdx.x * 2048 + threadIdx.x * 4;
    int myg[4]; unsigned myp[4]; float myw[4];
    if (i0 + 3 < e) {
        int4  r4 = *(const int4*)(row + i0);
        int4  c4 = *(const int4*)(col + i0);
        float4 w4 = *(const float4*)(w + i0);
        int cc[4] = {c4.x, c4.y, c4.z, c4.w};
        int rr[4] = {r4.x, r4.y, r4.z, r4.w};
        float wv[4] = {w4.x, w4.y, w4.z, w4.w};
#pragma unroll
        for (int k = 0; k < 4; ++k) {
            int g = batch[cc[k]];
            myg[k] = g; myw[k] = wv[k];
            myp[k] = ((unsigned)(cc[k] - lbs[g]) << 17) | (unsigned)rr[k];
            atomicAdd(&lcnt[g], 1);
        }
    } else {
#pragma unroll
        for (int k = 0; k < 4; ++k) {
            long i = i0 + k;
            myg[k] = -1;
            if (i < e) {
                int c = col[i];
                int g = batch[c];
                myg[k] = g; myw[k] = w[i];
                myp[k] = ((unsigned)(c - lbs[g]) << 17) | (unsigned)row[i];
                atomicAdd(&lcnt[g], 1);
            }
        }
    }
    __syncthreads();
    if (threadIdx.x < GG && lcnt[threadIdx.x])
        lres[threadIdx.x] = atomicAdd(&gcur[threadIdx.x], lcnt[threadIdx.x]);
    __syncthreads();
#pragma unroll
    for (int k = 0; k < 4; ++k) {
        if (myg[k] >= 0) {
            int slot = lres[myg[k]] + atomicAdd(&loff[myg[k]], 1);
            rec[slot] = make_float2(myw[k], __int_as_float((int)myp[k]));
        }
    }
}

// fused per-graph degree + hs: deg (LDS) -> dinv (LDS+global) -> hs16 for the slice.
__global__ void __launch_bounds__(256) deghs_kernel(
    const float2* __restrict__ rec, const int* __restrict__ gcur, const int* __restrict__ lb,
    const int* __restrict__ x, const float* __restrict__ emb, const float* __restrict__ Wc,
    float* __restrict__ dinv, __half2* __restrict__ hs16) {
    __shared__ float dl[MAXN];
    const int g = blockIdx.x;
    const int ns = lb[g], ne = lb[g + 1], sz = ne - ns;
    const long lo = (long)g * CAP, hi = gcur[g];
    if (sz <= MAXN) {
        for (int t = threadIdx.x; t < sz; t += 256) dl[t] = 2.0f;  // improved self-loop fill
        __syncthreads();
        for (long it = lo + threadIdx.x; it < hi; it += 256) {
            float2 r = rec[it];
            atomicAdd(&dl[(unsigned)__float_as_int(r.y) >> 17], r.x);
        }
        __syncthreads();
        for (int t = threadIdx.x; t < sz; t += 256) {
            float d = rsqrtf(dl[t]);
            dl[t] = d;
            dinv[ns + t] = d;
        }
        __syncthreads();
        for (int idx = threadIdx.x; idx < sz * 16; idx += 256) {
            int iL = idx >> 4, zp = idx & 15;
            int i = ns + iL;
            float d = dl[iL];
            const float* er = emb + (long)x[i] * EMBD;
            float a0 = 0.f, a1 = 0.f;
#pragma unroll
            for (int j = 0; j < EMBD; ++j) {
                float ej = er[j];
                a0 += ej * Wc[j * ZZDIM + 2 * zp];
                a1 += ej * Wc[j * ZZDIM + 2 * zp + 1];
            }
            hs16[(long)i * 16 + zp] = __floats2half2_rn(d * a0, d * a1);
        }
    } else {  // fallback (never expected at n/GG ~ 390): global accumulation
        for (int t = threadIdx.x; t < sz; t += 256) dinv[ns + t] = 2.0f;
        __syncthreads();
        for (long it = lo + threadIdx.x; it < hi; it += 256) {
            float2 r = rec[it];
            atomicAdd(&dinv[ns + ((unsigned)__float_as_int(r.y) >> 17)], r.x);
        }
        __syncthreads();
        for (int t = threadIdx.x; t < sz; t += 256) dinv[ns + t] = rsqrtf(dinv[ns + t]);
        __syncthreads();
        for (int idx = threadIdx.x; idx < sz * 16; idx += 256) {
            int iL = idx >> 4, zp = idx & 15;
            int i = ns + iL;
            float d = dinv[i];
            const float* er = emb + (long)x[i] * EMBD;
            float a0 = 0.f, a1 = 0.f;
#pragma unroll
            for (int j = 0; j < EMBD; ++j) {
                float ej = er[j];
                a0 += ej * Wc[j * ZZDIM + 2 * zp];
                a1 += ej * Wc[j * ZZDIM + 2 * zp + 1];
            }
            hs16[(long)i * 16 + zp] = __floats2half2_rn(d * a0, d * a1);
        }
    }
}

// Register-accumulation scatter over fp16 hs rows; the last-arriving of each graph's
// BPG blocks also performs the pooled+logits finalize (no separate kernel).
__global__ void __launch_bounds__(512) scatter_kernel(
    const float2* __restrict__ rec, const int* __restrict__ gcur,
    const int* __restrict__ lb, const float* __restrict__ dinv,
    const uint2* __restrict__ hsq, float* __restrict__ partial, int* __restrict__ pcnt,
    const float* __restrict__ bc, const float* __restrict__ Wr, float* __restrict__ out) {
    __shared__ float dl[MAXN];
    const int z4   = threadIdx.x & 7;        // channel quad 0..7
    const int slot = threadIdx.x >> 3;       // 0..63
    const int g = blockIdx.x >> 2;
    const int q = blockIdx.x & 3;
    const int sg = q * SLOTS + slot;         // slot-in-graph 0..255
    const int ns = lb[g], ne = lb[g + 1], sz = ne - ns;
    const bool inl = (sz <= MAXN);
    if (inl) for (int t = threadIdx.x; t < sz; t += 512) dl[t] = dinv[ns + t];
    __syncthreads();

    float4 acc = make_float4(0.f, 0.f, 0.f, 0.f);

#define GATHER4(pp) hsq[(long)((pp) & 0x1FFFFu) * 8 + z4]
#define ACCUM(c, v) do {                                              \
        float2 f0 = __half22float2(*(const __half2*)&(v).x);          \
        float2 f1 = __half22float2(*(const __half2*)&(v).y);          \
        acc.x = fmaf((c), f0.x, acc.x); acc.y = fmaf((c), f0.y, acc.y);\
        acc.z = fmaf((c), f1.x, acc.z); acc.w = fmaf((c), f1.y, acc.w);\
    } while (0)

    // edges of graph g (bucketed segment [g*CAP, gcur[g]))
    const long lo = (long)g * CAP;
    const long hi = gcur[g];
    long it = lo + sg;
    for (; it + 3L * SPG < hi; it += 4L * SPG) {
        float2 r0 = rec[it];
        float2 r1 = rec[it + SPG];
        float2 r2 = rec[it + 2L * SPG];
        float2 r3 = rec[it + 3L * SPG];
        unsigned p0 = (unsigned)__float_as_int(r0.y), p1 = (unsigned)__float_as_int(r1.y);
        unsigned p2 = (unsigned)__float_as_int(r2.y), p3 = (unsigned)__float_as_int(r3.y);
        uint2 v0 = GATHER4(p0);
        uint2 v1 = GATHER4(p1);
        uint2 v2 = GATHER4(p2);
        uint2 v3 = GATHER4(p3);
        float c0 = r0.x * (inl ? dl[p0 >> 17] : dinv[ns + (p0 >> 17)]);
        float c1 = r1.x * (inl ? dl[p1 >> 17] : dinv[ns + (p1 >> 17)]);
        float c2 = r2.x * (inl ? dl[p2 >> 17] : dinv[ns + (p2 >> 17)]);
        float c3 = r3.x * (inl ? dl[p3 >> 17] : dinv[ns + (p3 >> 17)]);
        ACCUM(c0, v0); ACCUM(c1, v1); ACCUM(c2, v2); ACCUM(c3, v3);
    }
    for (; it < hi; it += SPG) {
        float2 r = rec[it];
        unsigned p = (unsigned)__float_as_int(r.y);
        uint2 v = GATHER4(p);
        float c = r.x * (inl ? dl[p >> 17] : dinv[ns + (p >> 17)]);
        ACCUM(c, v);
    }

    // self-loops: nodes of graph g are contiguous [ns, ne)
    for (long i = ns + sg; i < ne; i += SPG) {
        float c2v = 2.0f * (inl ? dl[i - ns] : dinv[i]);
        uint2 v = hsq[i * 8 + z4];
        ACCUM(c2v, v);
    }
#undef GATHER4
#undef ACCUM

    // reduce 64 slots -> 32 channels
    __shared__ float4 s[SLOTS][8];
    __shared__ float4 s2[8][8];
    s[slot][z4] = acc;
    __syncthreads();
    if (threadIdx.x < 64) {
        int j = threadIdx.x & 7, part = threadIdx.x >> 3;
        float4 a = make_float4(0.f, 0.f, 0.f, 0.f);
#pragma unroll
        for (int k = 0; k < 8; ++k) {
            float4 b = s[part * 8 + k][j];
            a.x += b.x; a.y += b.y; a.z += b.z; a.w += b.w;
        }
        s2[part][j] = a;
    }
    __syncthreads();
    if (threadIdx.x < 8) {
        int j = threadIdx.x;
        float4 a = make_float4(0.f, 0.f, 0.f, 0.f);
#pragma unroll
        for (int k = 0; k < 8; ++k) {
            float4 b = s2[k][j];
            a.x += b.x; a.y += b.y; a.z += b.z; a.w += b.w;
        }
        *(float4*)&partial[(long)blockIdx.x * ZZDIM + j * 4] = a;
    }

    // ---- last-block-per-graph finalize ----
    __shared__ int win;
    __shared__ float p[ZZDIM];
    __threadfence();                 // order this block's partial stores before arrival
    __syncthreads();
    if (threadIdx.x == 0) {
        win = (atomicAdd(&pcnt[g], 1) == BPG - 1) ? 1 : 0;
        if (win) __threadfence();    // acquire: other blocks' partials now visible
    }
    __syncthreads();
    if (!win) return;
    if (threadIdx.x < ZZDIM) {
        int t = threadIdx.x;
        float a = 0.f;
#pragma unroll
        for (int qq = 0; qq < BPG; ++qq) a += partial[(long)(g * BPG + qq) * ZZDIM + t];
        float c = (float)sz;
        float v = (c > 0.f) ? (bc[t] + a / c) : 0.f;
        out[g * ZZDIM + t] = v;
        p[t] = v;
    }
    __syncthreads();
    if (threadIdx.x < KK) {
        int t = threadIdx.x;
        float a = 0.f;
#pragma unroll
        for (int zz = 0; zz < ZZDIM; ++zz) a += p[zz] * Wr[zz * KK + t];
        out[GG * ZZDIM + g * KK + t] = a;
    }
}

// ---------------- launch ----------------

extern "C" void kernel_launch(void* const* d_in, const int* in_sizes, int n_in,
                              void* d_out, int out_size, void* d_ws, size_t ws_size,
                              hipStream_t stream) {
    const int*   x     = (const int*)d_in[0];
    const int*   ei    = (const int*)d_in[1];   // [2,E]: rows then cols
    const float* ew    = (const float*)d_in[2];
    const int*   batch = (const int*)d_in[3];
    const float* emb   = (const float*)d_in[4];
    const float* Wc    = (const float*)d_in[5];
    const float* bc    = (const float*)d_in[6];
    const float* Wr    = (const float*)d_in[7];
    float* out = (float*)d_out;

    const int n = in_sizes[0];
    const int e = in_sizes[2];

    float* ws   = (float*)d_ws;
    __half2* hs16 = (__half2*)ws;            // n*16 half2 = 16n words (16 B aligned)
    float* dinv = ws + 16L * n;              // n
    int*  lb    = (int*)(ws + 17L * n);      // GG+1
    int*  gcur  = lb + GG + 1;               // GG
    int*  pcnt  = gcur + GG;                 // GG
    long rbase = 17L * n + (3 * GG + 1);
    rbase = (rbase + 63) & ~63L;
    float2* rec = (float2*)(ws + rbase);     // GG*CAP records (8 B each)
    long pbase = rbase + 2L * GG * CAP;
    pbase = (pbase + 63) & ~63L;
    float* partial = ws + pbase;             // SGRID*32 floats

    lb_kernel<<<1, 256, 0, stream>>>(batch, lb, gcur, pcnt, n);
    bucket_kernel<<<(e + 2047) / 2048, 512, 0, stream>>>(ei, ei + e, ew, batch, lb, gcur, rec, e);
    deghs_kernel<<<GG, 256, 0, stream>>>(rec, gcur, lb, x, emb, Wc, dinv, hs16);
    scatter_kernel<<<SGRID, 512, 0, stream>>>(rec, gcur, lb, dinv, (const uint2*)hs16,
                                              partial, pcnt, bc, Wr, out);
}

// Round 12
// 99.436 us; speedup vs baseline: 2.9719x; 2.9719x over previous
//
#include <hip/hip_runtime.h>
#include <hip/hip_fp16.h>

#define GG 256   // NUM_GRAPHS
#define ZZDIM 32 // Z
#define KK 64    // K
#define EMBD 10  // EMB
#define BPG 4                // scatter blocks per graph
#define SGRID (GG * BPG)     // 1024 scatter blocks
#define SLOTS 64             // slots per 512-thr scatter block (8 lanes each)
#define SPG (BPG * SLOTS)    // 256 slots per graph
#define MAXN 4096            // LDS node-slice capacity (graphs avg ~390 nodes)
#define CAP 16384            // per-graph record segment capacity (avg fill 6250, 24+ sigma)

// Record: rec[i] = (w, bits(colLocal<<17 | row)); row < 2^17 (n=100000), colLocal < 2^15.
// hs is fp16: one 64 B line per node row — each edge gather touches exactly one line.
// NOTE (round-11 lesson): NO device-scope fences anywhere — __threadfence() on gfx950
// writes back + invalidates L2 (XCD non-coherence) and destroys gather cache residency.

// ---------------- kernels ----------------

// node ranges per graph (binary search on sorted batch); init segment cursors
__global__ void lb_kernel(const int* __restrict__ batch, int* __restrict__ lb,
                          int* __restrict__ gcur, int n) {
    int g = threadIdx.x;  // 256 threads
    int lo = 0, hi = n;
    while (lo < hi) {
        int mid = (lo + hi) >> 1;
        if (batch[mid] < g) lo = mid + 1; else hi = mid;
    }
    lb[g] = lo;
    if (g == 0) lb[GG] = n;
    gcur[g] = g * CAP;
}

// single-pass counting-bucket, 2048 edges/block, int4/float4 edge reads.
__global__ void __launch_bounds__(512) bucket_kernel(
    const int* __restrict__ row, const int* __restrict__ col, const float* __restrict__ w,
    const int* __restrict__ batch, const int* __restrict__ lb,
    int* __restrict__ gcur, float2* __restrict__ rec, int e) {
    __shared__ int lcnt[GG], lres[GG], loff[GG], lbs[GG];
    if (threadIdx.x < GG) { lcnt[threadIdx.x] = 0; loff[threadIdx.x] = 0; lbs[threadIdx.x] = lb[threadIdx.x]; }
    __syncthreads();
    const long i0 = (long)blockIdx.x * 2048 + threadIdx.x * 4;
    int myg[4]; unsigned myp[4]; float myw[4];
    if (i0 + 3 < e) {
        int4  r4 = *(const int4*)(row + i0);
        int4  c4 = *(const int4*)(col + i0);
        float4 w4 = *(const float4*)(w + i0);
        int cc[4] = {c4.x, c4.y, c4.z, c4.w};
        int rr[4] = {r4.x, r4.y, r4.z, r4.w};
        float wv[4] = {w4.x, w4.y, w4.z, w4.w};
#pragma unroll
        for (int k = 0; k < 4; ++k) {
            int g = batch[cc[k]];
            myg[k] = g; myw[k] = wv[k];
            myp[k] = ((unsigned)(cc[k] - lbs[g]) << 17) | (unsigned)rr[k];
            atomicAdd(&lcnt[g], 1);
        }
    } else {
#pragma unroll
        for (int k = 0; k < 4; ++k) {
            long i = i0 + k;
            myg[k] = -1;
            if (i < e) {
                int c = col[i];
                int g = batch[c];
                myg[k] = g; myw[k] = w[i];
                myp[k] = ((unsigned)(c - lbs[g]) << 17) | (unsigned)row[i];
                atomicAdd(&lcnt[g], 1);
            }
        }
    }
    __syncthreads();
    if (threadIdx.x < GG && lcnt[threadIdx.x])
        lres[threadIdx.x] = atomicAdd(&gcur[threadIdx.x], lcnt[threadIdx.x]);
    __syncthreads();
#pragma unroll
    for (int k = 0; k < 4; ++k) {
        if (myg[k] >= 0) {
            int slot = lres[myg[k]] + atomicAdd(&loff[myg[k]], 1);
            rec[slot] = make_float2(myw[k], __int_as_float((int)myp[k]));
        }
    }
}

// fused per-graph degree + hs: deg (LDS) -> dinv (LDS+global) -> hs16 for the slice.
__global__ void __launch_bounds__(256) deghs_kernel(
    const float2* __restrict__ rec, const int* __restrict__ gcur, const int* __restrict__ lb,
    const int* __restrict__ x, const float* __restrict__ emb, const float* __restrict__ Wc,
    float* __restrict__ dinv, __half2* __restrict__ hs16) {
    __shared__ float dl[MAXN];
    const int g = blockIdx.x;
    const int ns = lb[g], ne = lb[g + 1], sz = ne - ns;
    const long lo = (long)g * CAP, hi = gcur[g];
    if (sz <= MAXN) {
        for (int t = threadIdx.x; t < sz; t += 256) dl[t] = 2.0f;  // improved self-loop fill
        __syncthreads();
        for (long it = lo + threadIdx.x; it < hi; it += 256) {
            float2 r = rec[it];
            atomicAdd(&dl[(unsigned)__float_as_int(r.y) >> 17], r.x);
        }
        __syncthreads();
        for (int t = threadIdx.x; t < sz; t += 256) {
            float d = rsqrtf(dl[t]);
            dl[t] = d;
            dinv[ns + t] = d;
        }
        __syncthreads();
        for (int idx = threadIdx.x; idx < sz * 16; idx += 256) {
            int iL = idx >> 4, zp = idx & 15;
            int i = ns + iL;
            float d = dl[iL];
            const float* er = emb + (long)x[i] * EMBD;
            float a0 = 0.f, a1 = 0.f;
#pragma unroll
            for (int j = 0; j < EMBD; ++j) {
                float ej = er[j];
                a0 += ej * Wc[j * ZZDIM + 2 * zp];
                a1 += ej * Wc[j * ZZDIM + 2 * zp + 1];
            }
            hs16[(long)i * 16 + zp] = __floats2half2_rn(d * a0, d * a1);
        }
    } else {  // fallback (never expected at n/GG ~ 390): global accumulation
        for (int t = threadIdx.x; t < sz; t += 256) dinv[ns + t] = 2.0f;
        __syncthreads();
        for (long it = lo + threadIdx.x; it < hi; it += 256) {
            float2 r = rec[it];
            atomicAdd(&dinv[ns + ((unsigned)__float_as_int(r.y) >> 17)], r.x);
        }
        __syncthreads();
        for (int t = threadIdx.x; t < sz; t += 256) dinv[ns + t] = rsqrtf(dinv[ns + t]);
        __syncthreads();
        for (int idx = threadIdx.x; idx < sz * 16; idx += 256) {
            int iL = idx >> 4, zp = idx & 15;
            int i = ns + iL;
            float d = dinv[i];
            const float* er = emb + (long)x[i] * EMBD;
            float a0 = 0.f, a1 = 0.f;
#pragma unroll
            for (int j = 0; j < EMBD; ++j) {
                float ej = er[j];
                a0 += ej * Wc[j * ZZDIM + 2 * zp];
                a1 += ej * Wc[j * ZZDIM + 2 * zp + 1];
            }
            hs16[(long)i * 16 + zp] = __floats2half2_rn(d * a0, d * a1);
        }
    }
}

// Register-accumulation scatter over fp16 hs rows (64 B): 8 lanes x uint2 per edge.
// Plain partial stores only — finalize is a separate kernel (no fences!).
__global__ void __launch_bounds__(512) scatter_kernel(
    const float2* __restrict__ rec, const int* __restrict__ gcur,
    const int* __restrict__ lb, const float* __restrict__ dinv,
    const uint2* __restrict__ hsq, float* __restrict__ partial) {
    __shared__ float dl[MAXN];
    const int z4   = threadIdx.x & 7;        // channel quad 0..7
    const int slot = threadIdx.x >> 3;       // 0..63
    const int g = blockIdx.x >> 2;
    const int q = blockIdx.x & 3;
    const int sg = q * SLOTS + slot;         // slot-in-graph 0..255
    const int ns = lb[g], ne = lb[g + 1], sz = ne - ns;
    const bool inl = (sz <= MAXN);
    if (inl) for (int t = threadIdx.x; t < sz; t += 512) dl[t] = dinv[ns + t];
    __syncthreads();

    float4 acc = make_float4(0.f, 0.f, 0.f, 0.f);

#define GATHER4(pp) hsq[(long)((pp) & 0x1FFFFu) * 8 + z4]
#define ACCUM(c, v) do {                                              \
        float2 f0 = __half22float2(*(const __half2*)&(v).x);          \
        float2 f1 = __half22float2(*(const __half2*)&(v).y);          \
        acc.x = fmaf((c), f0.x, acc.x); acc.y = fmaf((c), f0.y, acc.y);\
        acc.z = fmaf((c), f1.x, acc.z); acc.w = fmaf((c), f1.y, acc.w);\
    } while (0)

    // edges of graph g (bucketed segment [g*CAP, gcur[g]))
    const long lo = (long)g * CAP;
    const long hi = gcur[g];
    long it = lo + sg;
    for (; it + 3L * SPG < hi; it += 4L * SPG) {
        float2 r0 = rec[it];
        float2 r1 = rec[it + SPG];
        float2 r2 = rec[it + 2L * SPG];
        float2 r3 = rec[it + 3L * SPG];
        unsigned p0 = (unsigned)__float_as_int(r0.y), p1 = (unsigned)__float_as_int(r1.y);
        unsigned p2 = (unsigned)__float_as_int(r2.y), p3 = (unsigned)__float_as_int(r3.y);
        uint2 v0 = GATHER4(p0);
        uint2 v1 = GATHER4(p1);
        uint2 v2 = GATHER4(p2);
        uint2 v3 = GATHER4(p3);
        float c0 = r0.x * (inl ? dl[p0 >> 17] : dinv[ns + (p0 >> 17)]);
        float c1 = r1.x * (inl ? dl[p1 >> 17] : dinv[ns + (p1 >> 17)]);
        float c2 = r2.x * (inl ? dl[p2 >> 17] : dinv[ns + (p2 >> 17)]);
        float c3 = r3.x * (inl ? dl[p3 >> 17] : dinv[ns + (p3 >> 17)]);
        ACCUM(c0, v0); ACCUM(c1, v1); ACCUM(c2, v2); ACCUM(c3, v3);
    }
    for (; it < hi; it += SPG) {
        float2 r = rec[it];
        unsigned p = (unsigned)__float_as_int(r.y);
        uint2 v = GATHER4(p);
        float c = r.x * (inl ? dl[p >> 17] : dinv[ns + (p >> 17)]);
        ACCUM(c, v);
    }

    // self-loops: nodes of graph g are contiguous [ns, ne)
    for (long i = ns + sg; i < ne; i += SPG) {
        float c2v = 2.0f * (inl ? dl[i - ns] : dinv[i]);
        uint2 v = hsq[i * 8 + z4];
        ACCUM(c2v, v);
    }
#undef GATHER4
#undef ACCUM

    // reduce 64 slots -> 32 channels
    __shared__ float4 s[SLOTS][8];
    __shared__ float4 s2[8][8];
    s[slot][z4] = acc;
    __syncthreads();
    if (threadIdx.x < 64) {
        int j = threadIdx.x & 7, part = threadIdx.x >> 3;
        float4 a = make_float4(0.f, 0.f, 0.f, 0.f);
#pragma unroll
        for (int k = 0; k < 8; ++k) {
            float4 b = s[part * 8 + k][j];
            a.x += b.x; a.y += b.y; a.z += b.z; a.w += b.w;
        }
        s2[part][j] = a;
    }
    __syncthreads();
    if (threadIdx.x < 8) {
        int j = threadIdx.x;
        float4 a = make_float4(0.f, 0.f, 0.f, 0.f);
#pragma unroll
        for (int k = 0; k < 8; ++k) {
            float4 b = s2[k][j];
            a.x += b.x; a.y += b.y; a.z += b.z; a.w += b.w;
        }
        *(float4*)&partial[(long)blockIdx.x * ZZDIM + j * 4] = a;
    }
}

// sum BPG partials per graph -> pooled -> logits
__global__ void finalize_kernel(const float* __restrict__ partial, const int* __restrict__ lb,
                                const float* __restrict__ bc, const float* __restrict__ Wr,
                                float* __restrict__ out) {
    int g = blockIdx.x;
    int t = threadIdx.x;  // 64 threads
    __shared__ float p[ZZDIM];
    if (t < ZZDIM) {
        float a = 0.f;
#pragma unroll
        for (int q = 0; q < BPG; ++q) a += partial[(long)(g * BPG + q) * ZZDIM + t];
        float c = (float)(lb[g + 1] - lb[g]);
        float v = (c > 0.f) ? (bc[t] + a / c) : 0.f;
        out[g * ZZDIM + t] = v;
        p[t] = v;
    }
    __syncthreads();
    float a = 0.f;
#pragma unroll
    for (int zz = 0; zz < ZZDIM; ++zz) a += p[zz] * Wr[zz * KK + t];
    out[GG * ZZDIM + g * KK + t] = a;
}

// ---------------- launch ----------------

extern "C" void kernel_launch(void* const* d_in, const int* in_sizes, int n_in,
                              void* d_out, int out_size, void* d_ws, size_t ws_size,
                              hipStream_t stream) {
    const int*   x     = (const int*)d_in[0];
    const int*   ei    = (const int*)d_in[1];   // [2,E]: rows then cols
    const float* ew    = (const float*)d_in[2];
    const int*   batch = (const int*)d_in[3];
    const float* emb   = (const float*)d_in[4];
    const float* Wc    = (const float*)d_in[5];
    const float* bc    = (const float*)d_in[6];
    const float* Wr    = (const float*)d_in[7];
    float* out = (float*)d_out;

    const int n = in_sizes[0];
    const int e = in_sizes[2];

    float* ws   = (float*)d_ws;
    __half2* hs16 = (__half2*)ws;            // n*16 half2 = 16n words (16 B aligned)
    float* dinv = ws + 16L * n;              // n
    int*  lb    = (int*)(ws + 17L * n);      // GG+1
    int*  gcur  = lb + GG + 1;               // GG
    long rbase = 17L * n + (2 * GG + 1);
    rbase = (rbase + 63) & ~63L;
    float2* rec = (float2*)(ws + rbase);     // GG*CAP records (8 B each)
    long pbase = rbase + 2L * GG * CAP;
    pbase = (pbase + 63) & ~63L;
    float* partial = ws + pbase;             // SGRID*32 floats

    lb_kernel<<<1, 256, 0, stream>>>(batch, lb, gcur, n);
    bucket_kernel<<<(e + 2047) / 2048, 512, 0, stream>>>(ei, ei + e, ew, batch, lb, gcur, rec, e);
    deghs_kernel<<<GG, 256, 0, stream>>>(rec, gcur, lb, x, emb, Wc, dinv, hs16);
    scatter_kernel<<<SGRID, 512, 0, stream>>>(rec, gcur, lb, dinv, (const uint2*)hs16, partial);
    finalize_kernel<<<GG, KK, 0, stream>>>(partial, lb, bc, Wr, out);
}

// Round 13
// 83.979 us; speedup vs baseline: 3.5189x; 1.1841x over previous
//
#include <hip/hip_runtime.h>
#include <hip/hip_fp16.h>

#define GG 256   // NUM_GRAPHS
#define ZZDIM 32 // Z
#define KK 64    // K
#define EMBD 10  // EMB
#define BPG 4                // scatter blocks per graph
#define SGRID (GG * BPG)     // 1024 scatter blocks
#define SLOTS 64             // slots per 512-thr scatter block (8 lanes each)
#define SPG (BPG * SLOTS)    // 256 slots per graph
#define MAXN 1024            // LDS node-slice capacity (sizes ~390±20, 32-sigma bound; fallback kept)
#define CAP 16384            // per-graph record segment capacity (avg fill 6250, 24+ sigma)

// Record: rec[i] = (w, bits(colLocal<<17 | row)); row < 2^17 (n=100000), colLocal < 2^15.
// hs is fp16: one 64 B line per node row — each edge gather touches exactly one line.
// Round-11 lesson: NO device-scope fences (__threadfence hits all XCD L2s).
// Round-12 lesson: do NOT fuse per-graph (256-block) kernels with n-parallel work —
// occupancy collapse costs more than a launch.

// ---------------- kernels ----------------

// node ranges per graph (binary search on sorted batch); init segment cursors
__global__ void lb_kernel(const int* __restrict__ batch, int* __restrict__ lb,
                          int* __restrict__ gcur, int n) {
    int g = threadIdx.x;  // 256 threads
    int lo = 0, hi = n;
    while (lo < hi) {
        int mid = (lo + hi) >> 1;
        if (batch[mid] < g) lo = mid + 1; else hi = mid;
    }
    lb[g] = lo;
    if (g == 0) lb[GG] = n;
    gcur[g] = g * CAP;
}

// single-pass counting-bucket: g = batch[col] inline (L2-hit), block-run reservation
// via 256 global cursor atomics, records into fixed-capacity per-graph segments.
__global__ void __launch_bounds__(512) bucket_kernel(
    const int* __restrict__ row, const int* __restrict__ col, const float* __restrict__ w,
    const int* __restrict__ batch, const int* __restrict__ lb,
    int* __restrict__ gcur, float2* __restrict__ rec, int e) {
    __shared__ int lcnt[GG], lres[GG], loff[GG], lbs[GG];
    for (int t = threadIdx.x; t < GG; t += 512) { lcnt[t] = 0; loff[t] = 0; lbs[t] = lb[t]; }
    __syncthreads();
    const long start = (long)blockIdx.x * 8192;
    int myg[16]; unsigned myp[16];
#pragma unroll
    for (int k = 0; k < 16; ++k) {
        long i = start + k * 512 + threadIdx.x;
        int g = -1;
        if (i < e) {
            int c = col[i];
            g = batch[c];
            myp[k] = ((unsigned)(c - lbs[g]) << 17) | (unsigned)row[i];
            atomicAdd(&lcnt[g], 1);
        }
        myg[k] = g;
    }
    __syncthreads();
    for (int t = threadIdx.x; t < GG; t += 512)
        if (lcnt[t]) lres[t] = atomicAdd(&gcur[t], lcnt[t]);
    __syncthreads();
#pragma unroll
    for (int k = 0; k < 16; ++k) {
        long i = start + k * 512 + threadIdx.x;
        if (i < e) {
            int g = myg[k];
            int slot = lres[g] + atomicAdd(&loff[g], 1);
            rec[slot] = make_float2(w[i], __int_as_float((int)myp[k]));
        }
    }
}

// per-graph degree via LDS accumulation over the graph's contiguous node slice;
// writes dinv = rsqrt(deg). One block per graph — NO device-scope atomics.
__global__ void degB_kernel(const float2* __restrict__ rec, const int* __restrict__ gcur,
                            const int* __restrict__ lb, float* __restrict__ dinv) {
    __shared__ float dl[MAXN];
    const int g = blockIdx.x;
    const int ns = lb[g], ne = lb[g + 1], sz = ne - ns;
    const long lo = (long)g * CAP;
    const long hi = gcur[g];
    if (sz <= MAXN) {
        for (int t = threadIdx.x; t < sz; t += 256) dl[t] = 2.0f;  // improved self-loop fill
        __syncthreads();
        for (long it = lo + threadIdx.x; it < hi; it += 256) {
            float2 r = rec[it];
            atomicAdd(&dl[(unsigned)__float_as_int(r.y) >> 17], r.x);
        }
        __syncthreads();
        for (int t = threadIdx.x; t < sz; t += 256) dinv[ns + t] = rsqrtf(dl[t]);
    } else {  // fallback (never expected at n/GG ~ 390)
        for (int t = threadIdx.x; t < sz; t += 256) dinv[ns + t] = 2.0f;
        __syncthreads();
        for (long it = lo + threadIdx.x; it < hi; it += 256) {
            float2 r = rec[it];
            atomicAdd(&dinv[ns + ((unsigned)__float_as_int(r.y) >> 17)], r.x);
        }
        __syncthreads();
        for (int t = threadIdx.x; t < sz; t += 256) dinv[ns + t] = rsqrtf(dinv[ns + t]);
    }
}

// hs16[i, 2zp..2zp+1] = half2( dinv[i] * sum_j embed[x[i],j] * Wc[j, 2zp..2zp+1] )
__global__ void hs_kernel(const int* __restrict__ x, const float* __restrict__ emb,
                          const float* __restrict__ Wc, const float* __restrict__ dinv,
                          __half2* __restrict__ hs16, int n) {
    int tid = blockIdx.x * blockDim.x + threadIdx.x;
    int i = tid >> 4, zp = tid & 15;     // 16 half2 per node row
    if (i >= n) return;
    float d = dinv[i];
    int xi = x[i];
    const float* er = emb + (long)xi * EMBD;
    float a0 = 0.f, a1 = 0.f;
#pragma unroll
    for (int j = 0; j < EMBD; ++j) {
        float ej = er[j];
        a0 += ej * Wc[j * ZZDIM + 2 * zp];
        a1 += ej * Wc[j * ZZDIM + 2 * zp + 1];
    }
    hs16[(long)i * 16 + zp] = __floats2half2_rn(d * a0, d * a1);
}

// Register-accumulation scatter over fp16 hs rows (64 B): 8 lanes x uint2 per edge.
__global__ void __launch_bounds__(512) scatter_kernel(
    const float2* __restrict__ rec, const int* __restrict__ gcur,
    const int* __restrict__ lb, const float* __restrict__ dinv,
    const uint2* __restrict__ hsq, float* __restrict__ partial) {
    __shared__ float dl[MAXN];
    const int z4   = threadIdx.x & 7;        // channel quad 0..7
    const int slot = threadIdx.x >> 3;       // 0..63
    const int g = blockIdx.x >> 2;
    const int q = blockIdx.x & 3;
    const int sg = q * SLOTS + slot;         // slot-in-graph 0..255
    const int ns = lb[g], ne = lb[g + 1], sz = ne - ns;
    const bool inl = (sz <= MAXN);
    if (inl) for (int t = threadIdx.x; t < sz; t += 512) dl[t] = dinv[ns + t];
    __syncthreads();

    float4 acc = make_float4(0.f, 0.f, 0.f, 0.f);

#define GATHER4(pp) hsq[(long)((pp) & 0x1FFFFu) * 8 + z4]
#define ACCUM(c, v) do {                                              \
        float2 f0 = __half22float2(*(const __half2*)&(v).x);          \
        float2 f1 = __half22float2(*(const __half2*)&(v).y);          \
        acc.x = fmaf((c), f0.x, acc.x); acc.y = fmaf((c), f0.y, acc.y);\
        acc.z = fmaf((c), f1.x, acc.z); acc.w = fmaf((c), f1.y, acc.w);\
    } while (0)

    // edges of graph g (bucketed segment [g*CAP, gcur[g]))
    const long lo = (long)g * CAP;
    const long hi = gcur[g];
    long it = lo + sg;
    for (; it + 3L * SPG < hi; it += 4L * SPG) {
        float2 r0 = rec[it];
        float2 r1 = rec[it + SPG];
        float2 r2 = rec[it + 2L * SPG];
        float2 r3 = rec[it + 3L * SPG];
        unsigned p0 = (unsigned)__float_as_int(r0.y), p1 = (unsigned)__float_as_int(r1.y);
        unsigned p2 = (unsigned)__float_as_int(r2.y), p3 = (unsigned)__float_as_int(r3.y);
        uint2 v0 = GATHER4(p0);
        uint2 v1 = GATHER4(p1);
        uint2 v2 = GATHER4(p2);
        uint2 v3 = GATHER4(p3);
        float c0 = r0.x * (inl ? dl[p0 >> 17] : dinv[ns + (p0 >> 17)]);
        float c1 = r1.x * (inl ? dl[p1 >> 17] : dinv[ns + (p1 >> 17)]);
        float c2 = r2.x * (inl ? dl[p2 >> 17] : dinv[ns + (p2 >> 17)]);
        float c3 = r3.x * (inl ? dl[p3 >> 17] : dinv[ns + (p3 >> 17)]);
        ACCUM(c0, v0); ACCUM(c1, v1); ACCUM(c2, v2); ACCUM(c3, v3);
    }
    for (; it < hi; it += SPG) {
        float2 r = rec[it];
        unsigned p = (unsigned)__float_as_int(r.y);
        uint2 v = GATHER4(p);
        float c = r.x * (inl ? dl[p >> 17] : dinv[ns + (p >> 17)]);
        ACCUM(c, v);
    }

    // self-loops: nodes of graph g are contiguous [ns, ne)
    for (long i = ns + sg; i < ne; i += SPG) {
        float c2v = 2.0f * (inl ? dl[i - ns] : dinv[i]);
        uint2 v = hsq[i * 8 + z4];
        ACCUM(c2v, v);
    }
#undef GATHER4
#undef ACCUM

    // reduce 64 slots -> 32 channels
    __shared__ float4 s[SLOTS][8];
    __shared__ float4 s2[8][8];
    s[slot][z4] = acc;
    __syncthreads();
    if (threadIdx.x < 64) {
        int j = threadIdx.x & 7, part = threadIdx.x >> 3;
        float4 a = make_float4(0.f, 0.f, 0.f, 0.f);
#pragma unroll
        for (int k = 0; k < 8; ++k) {
            float4 b = s[part * 8 + k][j];
            a.x += b.x; a.y += b.y; a.z += b.z; a.w += b.w;
        }
        s2[part][j] = a;
    }
    __syncthreads();
    if (threadIdx.x < 8) {
        int j = threadIdx.x;
        float4 a = make_float4(0.f, 0.f, 0.f, 0.f);
#pragma unroll
        for (int k = 0; k < 8; ++k) {
            float4 b = s2[k][j];
            a.x += b.x; a.y += b.y; a.z += b.z; a.w += b.w;
        }
        *(float4*)&partial[(long)blockIdx.x * ZZDIM + j * 4] = a;
    }
}

// sum BPG partials per graph -> pooled -> logits
__global__ void finalize_kernel(const float* __restrict__ partial, const int* __restrict__ lb,
                                const float* __restrict__ bc, const float* __restrict__ Wr,
                                float* __restrict__ out) {
    int g = blockIdx.x;
    int t = threadIdx.x;  // 64 threads
    __shared__ float p[ZZDIM];
    if (t < ZZDIM) {
        float a = 0.f;
#pragma unroll
        for (int q = 0; q < BPG; ++q) a += partial[(long)(g * BPG + q) * ZZDIM + t];
        float c = (float)(lb[g + 1] - lb[g]);
        float v = (c > 0.f) ? (bc[t] + a / c) : 0.f;
        out[g * ZZDIM + t] = v;
        p[t] = v;
    }
    __syncthreads();
    float a = 0.f;
#pragma unroll
    for (int zz = 0; zz < ZZDIM; ++zz) a += p[zz] * Wr[zz * KK + t];
    out[GG * ZZDIM + g * KK + t] = a;
}

// ---------------- launch ----------------

extern "C" void kernel_launch(void* const* d_in, const int* in_sizes, int n_in,
                              void* d_out, int out_size, void* d_ws, size_t ws_size,
                              hipStream_t stream) {
    const int*   x     = (const int*)d_in[0];
    const int*   ei    = (const int*)d_in[1];   // [2,E]: rows then cols
    const float* ew    = (const float*)d_in[2];
    const int*   batch = (const int*)d_in[3];
    const float* emb   = (const float*)d_in[4];
    const float* Wc    = (const float*)d_in[5];
    const float* bc    = (const float*)d_in[6];
    const float* Wr    = (const float*)d_in[7];
    float* out = (float*)d_out;

    const int n = in_sizes[0];
    const int e = in_sizes[2];

    float* ws   = (float*)d_ws;
    __half2* hs16 = (__half2*)ws;            // n*16 half2 = 16n words (16 B aligned)
    float* dinv = ws + 16L * n;              // n
    int*  lb    = (int*)(ws + 17L * n);      // GG+1
    int*  gcur  = lb + GG + 1;               // GG
    long rbase = 17L * n + (2 * GG + 1);
    rbase = (rbase + 63) & ~63L;
    float2* rec = (float2*)(ws + rbase);     // GG*CAP records (8 B each)
    long pbase = rbase + 2L * GG * CAP;
    pbase = (pbase + 63) & ~63L;
    float* partial = ws + pbase;             // SGRID*32 floats

    lb_kernel<<<1, 256, 0, stream>>>(batch, lb, gcur, n);
    bucket_kernel<<<(e + 8191) / 8192, 512, 0, stream>>>(ei, ei + e, ew, batch, lb, gcur, rec, e);
    degB_kernel<<<GG, 256, 0, stream>>>(rec, gcur, lb, dinv);
    hs_kernel<<<(n * 16 + 255) / 256, 256, 0, stream>>>(x, emb, Wc, dinv, hs16, n);
    scatter_kernel<<<SGRID, 512, 0, stream>>>(rec, gcur, lb, dinv, (const uint2*)hs16, partial);
    finalize_kernel<<<GG, KK, 0, stream>>>(partial, lb, bc, Wr, out);
}